// Round 4
// baseline (956.262 us; speedup 1.0000x reference)
//
#include <hip/hip_runtime.h>
#include <math.h>

// ---------------------------------------------------------------------------
// Encoder: GCN(2 layers) + per-graph mean pool + FF MLP on pooled rows + sigmoid
// N=100000 nodes, E=1600000 edges, D=128, G=256 graphs (graph_id sorted)
// Round 4:
//  - CSR build via 512-bucket two-pass counting sort (fill_csr was 122us of
//    scattered 8B writes => 100MB of partial-line evictions; bucketed writes
//    stay L2-hot => ~20MB). Replaces count_dst + scan_a/b/c + fill_csr.
//  - SpMM gather matrices stored bf16 (RNE): halves the dominant gather
//    traffic (FETCH 390MB -> ~200MB per spmm). Accumulation stays fp32.
// ---------------------------------------------------------------------------

#define D 128
#define G 256
#define NB 512   // dst buckets for CSR build

__device__ __forceinline__ unsigned short f2bf(float f) {
    unsigned u = __float_as_uint(f);
    unsigned r = (u + 0x7fffu + ((u >> 16) & 1u)) >> 16;   // round-nearest-even
    return (unsigned short)r;
}

// ---- Tiled fp32 GEMM: Y_bf16[nrows x 128] = transform(X) @ W
template<bool BIAS_RELU>
__global__ __launch_bounds__(256, 2)
void gemm128(const float* __restrict__ X, const float* __restrict__ W,
             const float* __restrict__ bias, unsigned short* __restrict__ Y, int nrows) {
    __shared__ float Ws[64][128];
    __shared__ float Xs[32][129];
    const int tid = threadIdx.x;
    const int r0 = blockIdx.x * 32;

    for (int i = tid; i < 32 * 128; i += 256) {
        int r = i >> 7, k = i & 127;
        int gr = r0 + r;
        float v = (gr < nrows) ? X[(size_t)gr * D + k] : 0.f;
        if (BIAS_RELU) v = fmaxf(v + bias[k], 0.f);
        Xs[r][k] = v;
    }

    const int c0 = (tid & 63) * 2;
    const int rb = (tid >> 6) * 8;
    float2 acc[8];
#pragma unroll
    for (int i = 0; i < 8; i++) acc[i] = make_float2(0.f, 0.f);

    for (int kb = 0; kb < 128; kb += 64) {
        __syncthreads();
        for (int i = tid; i < 64 * 128; i += 256) {
            int k = i >> 7, c = i & 127;
            Ws[k][c] = W[(size_t)(kb + k) * D + c];
        }
        __syncthreads();
#pragma unroll 8
        for (int k = 0; k < 64; k++) {
            float w0 = Ws[k][c0], w1 = Ws[k][c0 + 1];
#pragma unroll
            for (int i = 0; i < 8; i++) {
                float xv = Xs[rb + i][kb + k];
                acc[i].x = fmaf(xv, w0, acc[i].x);
                acc[i].y = fmaf(xv, w1, acc[i].y);
            }
        }
    }
#pragma unroll
    for (int i = 0; i < 8; i++) {
        int gr = r0 + rb + i;
        if (gr < nrows) {
            ushort2 o;
            o.x = f2bf(acc[i].x);
            o.y = f2bf(acc[i].y);
            *(ushort2*)(Y + (size_t)gr * D + c0) = o;
        }
    }
}

// ======================= CSR build: 2-pass bucket sort ======================

// Phase A: per-block LDS histogram of dst buckets -> global bucket counts
__global__ __launch_bounds__(256)
void bucket_count(const int* __restrict__ dst, int* __restrict__ bcnt,
                  int ne, int rpb) {
    __shared__ int h[NB];
    for (int i = threadIdx.x; i < NB; i += 256) h[i] = 0;
    __syncthreads();
    for (int e = blockIdx.x * 256 + threadIdx.x; e < ne; e += gridDim.x * 256)
        atomicAdd(&h[dst[e] / rpb], 1);
    __syncthreads();
    for (int i = threadIdx.x; i < NB; i += 256)
        if (h[i]) atomicAdd(&bcnt[i], h[i]);
}

// Phase B: scan bucket counts -> bbase[NB+1], init cursors, row_ptr[n]=ne
__global__ __launch_bounds__(NB)
void bucket_scan(const int* __restrict__ bcnt, int* __restrict__ bbase,
                 int* __restrict__ bcur, int* __restrict__ row_ptr,
                 int ne, int n) {
    __shared__ int s[NB];
    int t = threadIdx.x;
    int v = bcnt[t];
    s[t] = v;
    __syncthreads();
    for (int off = 1; off < NB; off <<= 1) {
        int x = (t >= off) ? s[t - off] : 0;
        __syncthreads();
        s[t] += x;
        __syncthreads();
    }
    bbase[t + 1] = s[t];
    bcur[t] = s[t] - v;
    if (t == 0) { bbase[0] = 0; row_ptr[n] = ne; }
}

// Phase C: scatter edges into bucket-grouped intermediate (L2-local writes)
__global__ __launch_bounds__(256)
void bucket_scatter(const int* __restrict__ src, const int* __restrict__ dst,
                    const float* __restrict__ ew, int* __restrict__ bcur,
                    int2* __restrict__ tmp_sw, int* __restrict__ tmp_dst,
                    int ne, int rpb) {
    int e = blockIdx.x * 256 + threadIdx.x;
    if (e >= ne) return;
    int d = dst[e];
    int pos = atomicAdd(&bcur[d / rpb], 1);
    tmp_sw[pos] = make_int2(src[e], __float_as_int(ew[e]));
    tmp_dst[pos] = d;
}

// Phase D: per-bucket LDS counting sort over its rpb(<=256) local rows.
// Writes final ep (sequential, full lines) and row_ptr.
__global__ __launch_bounds__(256)
void bucket_sort(const int* __restrict__ tmp_dst, const int2* __restrict__ tmp_sw,
                 const int* __restrict__ bbase, int2* __restrict__ ep,
                 int* __restrict__ row_ptr, int n, int rpb) {
    __shared__ int cnt[256], scn[256], cur[256];
    int b = blockIdx.x, t = threadIdx.x;
    int e0 = bbase[b], e1 = bbase[b + 1];
    int r0 = b * rpb;
    cnt[t] = 0;
    __syncthreads();
    for (int i = e0 + t; i < e1; i += 256)
        atomicAdd(&cnt[tmp_dst[i] - r0], 1);
    __syncthreads();
    int v = cnt[t];
    scn[t] = v;
    __syncthreads();
    for (int off = 1; off < 256; off <<= 1) {
        int x = (t >= off) ? scn[t - off] : 0;
        __syncthreads();
        scn[t] += x;
        __syncthreads();
    }
    int ex = scn[t] - v;
    cur[t] = ex;
    int grow = r0 + t;
    if (t < rpb && grow < n) row_ptr[grow] = e0 + ex;
    __syncthreads();
    for (int i = e0 + t; i < e1; i += 256) {
        int r = tmp_dst[i] - r0;
        int pos = e0 + atomicAdd(&cur[r], 1);
        ep[pos] = tmp_sw[i];
    }
}

// ---- Row-parallel gather SpMM (bf16 X): one wave per row, lane owns 2 dims
__global__ __launch_bounds__(256)
void spmm_csr_bf16(const unsigned int* __restrict__ Xu, const int2* __restrict__ ep,
                   const int* __restrict__ rp, float* __restrict__ out, int nrows) {
    int row = blockIdx.x * 4 + (threadIdx.x >> 6);
    if (row >= nrows) return;
    int dp = threadIdx.x & 63;            // bf16-pair index (2 dims)
    int beg = rp[row], end = rp[row + 1];
    float a0x = 0.f, a0y = 0.f, a1x = 0.f, a1y = 0.f;
    int j = beg;
    for (; j + 1 < end; j += 2) {
        int2 e0 = ep[j], e1 = ep[j + 1];
        float w0 = __int_as_float(e0.y), w1 = __int_as_float(e1.y);
        unsigned u0 = Xu[(size_t)e0.x * 64 + dp];
        unsigned u1 = Xu[(size_t)e1.x * 64 + dp];
        a0x = fmaf(w0, __uint_as_float(u0 << 16), a0x);
        a0y = fmaf(w0, __uint_as_float(u0 & 0xffff0000u), a0y);
        a1x = fmaf(w1, __uint_as_float(u1 << 16), a1x);
        a1y = fmaf(w1, __uint_as_float(u1 & 0xffff0000u), a1y);
    }
    if (j < end) {
        int2 e0 = ep[j];
        float w0 = __int_as_float(e0.y);
        unsigned u0 = Xu[(size_t)e0.x * 64 + dp];
        a0x = fmaf(w0, __uint_as_float(u0 << 16), a0x);
        a0y = fmaf(w0, __uint_as_float(u0 & 0xffff0000u), a0y);
    }
    float2 r;
    r.x = a0x + a1x;
    r.y = a0y + a1y;
    *(float2*)(out + (size_t)row * D + dp * 2) = r;
}

// ======================= graph pooling + FF =================================

__global__ __launch_bounds__(256)
void bounds_kernel(const int* __restrict__ gid, int* __restrict__ ptr, int n) {
    int i = blockIdx.x * 256 + threadIdx.x;
    if (i >= n) return;
    int b = gid[i];
    int a = (i == 0) ? -1 : gid[i - 1];
    for (int g = a + 1; g <= b; g++) ptr[g] = i;
    if (i == n - 1) {
        for (int g = b + 1; g <= G; g++) ptr[g] = n;
    }
}

__global__ __launch_bounds__(512)
void pool_kernel(const float* __restrict__ S, const int* __restrict__ ptr,
                 const float* __restrict__ b2, float* __restrict__ pooled) {
    __shared__ float red[4][128];
    int g = blockIdx.x;
    int d = threadIdx.x & 127;
    int r = threadIdx.x >> 7;
    int beg = ptr[g], end = ptr[g + 1];
    float acc = 0.f;
    for (int n = beg + r; n < end; n += 4) acc += S[(size_t)n * D + d];
    red[r][d] = acc;
    __syncthreads();
    if (r == 0) {
        float s = red[0][d] + red[1][d] + red[2][d] + red[3][d];
        int cnt = end - beg;
        pooled[g * D + d] = (cnt > 0) ? (s / (float)cnt + b2[d]) : 0.f;
    }
}

__global__ __launch_bounds__(128)
void ff_kernel(const float* __restrict__ pooled,
               const float* __restrict__ W1, const float* __restrict__ b1,
               const float* __restrict__ W2, const float* __restrict__ b2,
               const float* __restrict__ W3, const float* __restrict__ b3,
               const float* __restrict__ Wsc, const float* __restrict__ bsc,
               float* __restrict__ ffout) {
    __shared__ float hx[D], za[D], zb[D];
    int g = blockIdx.x, d = threadIdx.x;
    hx[d] = pooled[g * D + d];
    __syncthreads();
    float s = b1[d];
    for (int k = 0; k < D; k++) s = fmaf(hx[k], W1[k * D + d], s);
    za[d] = fmaxf(s, 0.f);
    __syncthreads();
    s = b2[d];
    for (int k = 0; k < D; k++) s = fmaf(za[k], W2[k * D + d], s);
    zb[d] = fmaxf(s, 0.f);
    __syncthreads();
    s = b3[d];
    for (int k = 0; k < D; k++) s = fmaf(zb[k], W3[k * D + d], s);
    float z3 = fmaxf(s, 0.f);
    float sc = bsc[d];
    for (int k = 0; k < D; k++) sc = fmaf(hx[k], Wsc[k * D + d], sc);
    float v = z3 + sc;
    ffout[g * D + d] = 1.f / (1.f + expf(-v));
}

__global__ __launch_bounds__(256)
void scatter_kernel(const float* __restrict__ ffout, const int* __restrict__ gid,
                    float* __restrict__ out, int n) {
    unsigned idx = blockIdx.x * 256u + threadIdx.x;
    unsigned node = idx >> 5;
    if (node >= (unsigned)n) return;
    int d0 = (idx & 31) * 4;
    int g = gid[node];
    *(float4*)(out + (size_t)node * D + d0) = *(const float4*)(ffout + g * D + d0);
}

extern "C" void kernel_launch(void* const* d_in, const int* in_sizes, int n_in,
                              void* d_out, int out_size, void* d_ws, size_t ws_size,
                              hipStream_t stream) {
    const float* feat = (const float*)d_in[0];
    const float* ew   = (const float*)d_in[1];
    const float* W1   = (const float*)d_in[2];
    const float* b1   = (const float*)d_in[3];
    const float* W2   = (const float*)d_in[4];
    const float* b2   = (const float*)d_in[5];
    const float* ffW1 = (const float*)d_in[6];
    const float* ffb1 = (const float*)d_in[7];
    const float* ffW2 = (const float*)d_in[8];
    const float* ffb2 = (const float*)d_in[9];
    const float* ffW3 = (const float*)d_in[10];
    const float* ffb3 = (const float*)d_in[11];
    const float* ffWs = (const float*)d_in[12];
    const float* ffbs = (const float*)d_in[13];
    const int* esrc = (const int*)d_in[14];
    const int* edst = (const int*)d_in[15];
    const int* gid  = (const int*)d_in[16];

    const int N = in_sizes[0] / D;
    const int E = in_sizes[1];
    float* out = (float*)d_out;

    const int rpb = (N + NB - 1) / NB;   // dst rows per bucket (196)

    // workspace layout
    char* ws = (char*)d_ws;
    int2* ep = (int2*)ws;                                   // E int2 = 12.8MB
    unsigned short* A = (unsigned short*)(ep + E);          // N*128 bf16 = 25.6MB
    // CSR-build temporaries alias A (A written only after build completes)
    int2* tmp_sw = (int2*)A;                                // E int2 = 12.8MB
    int* tmp_dst = (int*)(tmp_sw + E);                      // E int  = 6.4MB (19.2 < 25.6 OK)
    float* pooled = (float*)(A + (size_t)N * D);            // G*D
    float* ffo = pooled + G * D;                            // G*D
    int* gptr = (int*)(ffo + G * D);                        // G+1
    int* row_ptr = gptr + G + 2;                            // N+1
    int* bcnt = row_ptr + N + 1;                            // NB
    int* bbase = bcnt + NB;                                 // NB+1
    int* bcur = bbase + NB + 1;                             // NB

    float* S = out;  // fp32 SpMM result buffer (reused; final scatter overwrites)

    const dim3 blk(256);
    const int gemmGrid = (N + 31) / 32;
    const int eGrid = (E + 255) / 256;
    const int nGrid = (N + 255) / 256;

    // ---- CSR build (bucketed counting sort by dst)
    hipMemsetAsync(bcnt, 0, NB * sizeof(int), stream);
    bucket_count<<<NB, blk, 0, stream>>>(edst, bcnt, E, rpb);
    bucket_scan<<<1, NB, 0, stream>>>(bcnt, bbase, bcur, row_ptr, E, N);
    bucket_scatter<<<eGrid, blk, 0, stream>>>(esrc, edst, ew, bcur, tmp_sw, tmp_dst, E, rpb);
    bucket_sort<<<NB, blk, 0, stream>>>(tmp_dst, tmp_sw, bbase, ep, row_ptr, N, rpb);

    // ---- graph boundaries from sorted gid
    bounds_kernel<<<nGrid, blk, 0, stream>>>(gid, gptr, N);

    // ---- pipeline (A stored bf16; S fp32)
    gemm128<false><<<gemmGrid, blk, 0, stream>>>(feat, W1, nullptr, A, N);
    spmm_csr_bf16<<<(N + 3) / 4, blk, 0, stream>>>((const unsigned int*)A, ep, row_ptr, S, N);
    gemm128<true><<<gemmGrid, blk, 0, stream>>>(S, W2, b1, A, N);
    spmm_csr_bf16<<<(N + 3) / 4, blk, 0, stream>>>((const unsigned int*)A, ep, row_ptr, S, N);

    // ---- per-graph mean pool + FF + scatter
    pool_kernel<<<G, 512, 0, stream>>>(S, gptr, b2, pooled);
    ff_kernel<<<G, 128, 0, stream>>>(pooled, ffW1, ffb1, ffW2, ffb2,
                                     ffW3, ffb3, ffWs, ffbs, ffo);
    scatter_kernel<<<(int)(((size_t)N * 32 + 255) / 256), blk, 0, stream>>>(ffo, gid, out, N);
}

// Round 5
// 494.907 us; speedup vs baseline: 1.9322x; 1.9322x over previous
//
#include <hip/hip_runtime.h>
#include <math.h>

// ---------------------------------------------------------------------------
// Encoder: GCN(2 layers) + per-graph mean pool + FF MLP on pooled rows + sigmoid
// N=100000 nodes, E=1600000 edges, D=128, G=256 graphs (graph_id sorted)
// Round 5: CSR build via ATOMIC-FREE radix partition.
//   Round-4 post-mortem: bucket_scatter's 1.6M global atomics on 512 cursors
//   = 479us of same-address serialization. Now each block's position in each
//   bucket is precomputed (count + scan), so the scatter uses only LDS
//   cursors local to the block. Zero global atomics in the whole build.
// ---------------------------------------------------------------------------

#define D 128
#define G 256
#define NB 512     // dst buckets (rows-per-bucket = ceil(N/NB) = 196 <= 256)
#define NBLK 512   // scatter blocks (each owns a contiguous edge chunk)

__device__ __forceinline__ unsigned short f2bf(float f) {
    unsigned u = __float_as_uint(f);
    unsigned r = (u + 0x7fffu + ((u >> 16) & 1u)) >> 16;   // round-nearest-even
    return (unsigned short)r;
}

// ---- Tiled fp32 GEMM: Y_bf16[nrows x 128] = transform(X) @ W
template<bool BIAS_RELU>
__global__ __launch_bounds__(256, 2)
void gemm128(const float* __restrict__ X, const float* __restrict__ W,
             const float* __restrict__ bias, unsigned short* __restrict__ Y, int nrows) {
    __shared__ float Ws[64][128];
    __shared__ float Xs[32][129];
    const int tid = threadIdx.x;
    const int r0 = blockIdx.x * 32;

    for (int i = tid; i < 32 * 128; i += 256) {
        int r = i >> 7, k = i & 127;
        int gr = r0 + r;
        float v = (gr < nrows) ? X[(size_t)gr * D + k] : 0.f;
        if (BIAS_RELU) v = fmaxf(v + bias[k], 0.f);
        Xs[r][k] = v;
    }

    const int c0 = (tid & 63) * 2;
    const int rb = (tid >> 6) * 8;
    float2 acc[8];
#pragma unroll
    for (int i = 0; i < 8; i++) acc[i] = make_float2(0.f, 0.f);

    for (int kb = 0; kb < 128; kb += 64) {
        __syncthreads();
        for (int i = tid; i < 64 * 128; i += 256) {
            int k = i >> 7, c = i & 127;
            Ws[k][c] = W[(size_t)(kb + k) * D + c];
        }
        __syncthreads();
#pragma unroll 8
        for (int k = 0; k < 64; k++) {
            float w0 = Ws[k][c0], w1 = Ws[k][c0 + 1];
#pragma unroll
            for (int i = 0; i < 8; i++) {
                float xv = Xs[rb + i][kb + k];
                acc[i].x = fmaf(xv, w0, acc[i].x);
                acc[i].y = fmaf(xv, w1, acc[i].y);
            }
        }
    }
#pragma unroll
    for (int i = 0; i < 8; i++) {
        int gr = r0 + rb + i;
        if (gr < nrows) {
            ushort2 o;
            o.x = f2bf(acc[i].x);
            o.y = f2bf(acc[i].y);
            *(ushort2*)(Y + (size_t)gr * D + c0) = o;
        }
    }
}

// ============== CSR build: atomic-free radix partition + bucket sort ========

// R1: per-block LDS histogram of its edge chunk -> counts[bucket][block]
__global__ __launch_bounds__(256)
void radix_count(const int* __restrict__ dst, int* __restrict__ counts,
                 int ne, int rpb, int chunk) {
    __shared__ int h[NB];
    for (int i = threadIdx.x; i < NB; i += 256) h[i] = 0;
    __syncthreads();
    int b = blockIdx.x;
    int lo = b * chunk, hi = min(lo + chunk, ne);
    for (int e = lo + threadIdx.x; e < hi; e += 256)
        atomicAdd(&h[dst[e] / rpb], 1);
    __syncthreads();
    for (int k = threadIdx.x; k < NB; k += 256)
        counts[k * NBLK + b] = h[k];
}

// R2: per-bucket exclusive scan over the NBLK block counts (in place);
// bucket total -> bsum[bucket]
__global__ __launch_bounds__(256)
void radix_scan_rel(int* __restrict__ counts, int* __restrict__ bsum) {
    __shared__ int s[256];
    int k = blockIdx.x, t = threadIdx.x;
    int base = k * NBLK + t * 2;
    int v0 = counts[base], v1 = counts[base + 1];
    int sum = v0 + v1;
    s[t] = sum;
    __syncthreads();
    for (int off = 1; off < 256; off <<= 1) {
        int x = (t >= off) ? s[t - off] : 0;
        __syncthreads();
        s[t] += x;
        __syncthreads();
    }
    int ex = s[t] - sum;
    counts[base] = ex;
    counts[base + 1] = ex + v0;
    if (t == 255) bsum[k] = s[255];
}

// R3: exclusive scan of bucket totals -> bbase[NB+1]; row_ptr[n] = ne
__global__ __launch_bounds__(NB)
void radix_base(const int* __restrict__ bsum, int* __restrict__ bbase,
                int* __restrict__ row_ptr, int ne, int n) {
    __shared__ int s[NB];
    int t = threadIdx.x;
    int v = bsum[t];
    s[t] = v;
    __syncthreads();
    for (int off = 1; off < NB; off <<= 1) {
        int x = (t >= off) ? s[t - off] : 0;
        __syncthreads();
        s[t] += x;
        __syncthreads();
    }
    bbase[t + 1] = s[t];
    if (t == 0) { bbase[0] = 0; row_ptr[n] = ne; }
}

// R4: scatter edges into bucket-grouped order. No global atomics: block b's
// region inside bucket k starts at bbase[k] + counts[k][b]; LDS cursors only.
__global__ __launch_bounds__(256)
void radix_scatter(const int* __restrict__ src, const int* __restrict__ dst,
                   const float* __restrict__ ew,
                   const int* __restrict__ counts, const int* __restrict__ bbase,
                   int2* __restrict__ tmp_sw, unsigned short* __restrict__ tmp_lr,
                   int ne, int rpb, int chunk) {
    __shared__ int cur[NB];
    int b = blockIdx.x;
    for (int k = threadIdx.x; k < NB; k += 256)
        cur[k] = bbase[k] + counts[k * NBLK + b];
    __syncthreads();
    int lo = b * chunk, hi = min(lo + chunk, ne);
    for (int e = lo + threadIdx.x; e < hi; e += 256) {
        int d = dst[e];
        int k = d / rpb;
        int pos = atomicAdd(&cur[k], 1);          // LDS atomic
        tmp_sw[pos] = make_int2(src[e], __float_as_int(ew[e]));
        tmp_lr[pos] = (unsigned short)(d - k * rpb);
    }
}

// R5: per-bucket LDS counting sort over its rpb(<=256) local rows.
__global__ __launch_bounds__(256)
void bucket_sort(const unsigned short* __restrict__ tmp_lr,
                 const int2* __restrict__ tmp_sw,
                 const int* __restrict__ bbase, int2* __restrict__ ep,
                 int* __restrict__ row_ptr, int n, int rpb) {
    __shared__ int cnt[256], scn[256], cur[256];
    int b = blockIdx.x, t = threadIdx.x;
    int e0 = bbase[b], e1 = bbase[b + 1];
    int r0 = b * rpb;
    cnt[t] = 0;
    __syncthreads();
    for (int i = e0 + t; i < e1; i += 256)
        atomicAdd(&cnt[tmp_lr[i]], 1);
    __syncthreads();
    int v = cnt[t];
    scn[t] = v;
    __syncthreads();
    for (int off = 1; off < 256; off <<= 1) {
        int x = (t >= off) ? scn[t - off] : 0;
        __syncthreads();
        scn[t] += x;
        __syncthreads();
    }
    int ex = scn[t] - v;
    cur[t] = ex;
    int grow = r0 + t;
    if (t < rpb && grow < n) row_ptr[grow] = e0 + ex;
    __syncthreads();
    for (int i = e0 + t; i < e1; i += 256) {
        int r = tmp_lr[i];
        int pos = e0 + atomicAdd(&cur[r], 1);     // LDS atomic
        ep[pos] = tmp_sw[i];
    }
}

// ---- Row-parallel gather SpMM (bf16 X): one wave per row, lane owns 2 dims
__global__ __launch_bounds__(256)
void spmm_csr_bf16(const unsigned int* __restrict__ Xu, const int2* __restrict__ ep,
                   const int* __restrict__ rp, float* __restrict__ out, int nrows) {
    int row = blockIdx.x * 4 + (threadIdx.x >> 6);
    if (row >= nrows) return;
    int dp = threadIdx.x & 63;            // bf16-pair index (2 dims)
    int beg = rp[row], end = rp[row + 1];
    float a0x = 0.f, a0y = 0.f, a1x = 0.f, a1y = 0.f;
    int j = beg;
    for (; j + 1 < end; j += 2) {
        int2 e0 = ep[j], e1 = ep[j + 1];
        float w0 = __int_as_float(e0.y), w1 = __int_as_float(e1.y);
        unsigned u0 = Xu[(size_t)e0.x * 64 + dp];
        unsigned u1 = Xu[(size_t)e1.x * 64 + dp];
        a0x = fmaf(w0, __uint_as_float(u0 << 16), a0x);
        a0y = fmaf(w0, __uint_as_float(u0 & 0xffff0000u), a0y);
        a1x = fmaf(w1, __uint_as_float(u1 << 16), a1x);
        a1y = fmaf(w1, __uint_as_float(u1 & 0xffff0000u), a1y);
    }
    if (j < end) {
        int2 e0 = ep[j];
        float w0 = __int_as_float(e0.y);
        unsigned u0 = Xu[(size_t)e0.x * 64 + dp];
        a0x = fmaf(w0, __uint_as_float(u0 << 16), a0x);
        a0y = fmaf(w0, __uint_as_float(u0 & 0xffff0000u), a0y);
    }
    float2 r;
    r.x = a0x + a1x;
    r.y = a0y + a1y;
    *(float2*)(out + (size_t)row * D + dp * 2) = r;
}

// ======================= graph pooling + FF =================================

__global__ __launch_bounds__(256)
void bounds_kernel(const int* __restrict__ gid, int* __restrict__ ptr, int n) {
    int i = blockIdx.x * 256 + threadIdx.x;
    if (i >= n) return;
    int b = gid[i];
    int a = (i == 0) ? -1 : gid[i - 1];
    for (int g = a + 1; g <= b; g++) ptr[g] = i;
    if (i == n - 1) {
        for (int g = b + 1; g <= G; g++) ptr[g] = n;
    }
}

__global__ __launch_bounds__(512)
void pool_kernel(const float* __restrict__ S, const int* __restrict__ ptr,
                 const float* __restrict__ b2, float* __restrict__ pooled) {
    __shared__ float red[4][128];
    int g = blockIdx.x;
    int d = threadIdx.x & 127;
    int r = threadIdx.x >> 7;
    int beg = ptr[g], end = ptr[g + 1];
    float acc = 0.f;
    for (int n = beg + r; n < end; n += 4) acc += S[(size_t)n * D + d];
    red[r][d] = acc;
    __syncthreads();
    if (r == 0) {
        float s = red[0][d] + red[1][d] + red[2][d] + red[3][d];
        int cnt = end - beg;
        pooled[g * D + d] = (cnt > 0) ? (s / (float)cnt + b2[d]) : 0.f;
    }
}

__global__ __launch_bounds__(128)
void ff_kernel(const float* __restrict__ pooled,
               const float* __restrict__ W1, const float* __restrict__ b1,
               const float* __restrict__ W2, const float* __restrict__ b2,
               const float* __restrict__ W3, const float* __restrict__ b3,
               const float* __restrict__ Wsc, const float* __restrict__ bsc,
               float* __restrict__ ffout) {
    __shared__ float hx[D], za[D], zb[D];
    int g = blockIdx.x, d = threadIdx.x;
    hx[d] = pooled[g * D + d];
    __syncthreads();
    float s = b1[d];
    for (int k = 0; k < D; k++) s = fmaf(hx[k], W1[k * D + d], s);
    za[d] = fmaxf(s, 0.f);
    __syncthreads();
    s = b2[d];
    for (int k = 0; k < D; k++) s = fmaf(za[k], W2[k * D + d], s);
    zb[d] = fmaxf(s, 0.f);
    __syncthreads();
    s = b3[d];
    for (int k = 0; k < D; k++) s = fmaf(zb[k], W3[k * D + d], s);
    float z3 = fmaxf(s, 0.f);
    float sc = bsc[d];
    for (int k = 0; k < D; k++) sc = fmaf(hx[k], Wsc[k * D + d], sc);
    float v = z3 + sc;
    ffout[g * D + d] = 1.f / (1.f + expf(-v));
}

__global__ __launch_bounds__(256)
void scatter_kernel(const float* __restrict__ ffout, const int* __restrict__ gid,
                    float* __restrict__ out, int n) {
    unsigned idx = blockIdx.x * 256u + threadIdx.x;
    unsigned node = idx >> 5;
    if (node >= (unsigned)n) return;
    int d0 = (idx & 31) * 4;
    int g = gid[node];
    *(float4*)(out + (size_t)node * D + d0) = *(const float4*)(ffout + g * D + d0);
}

extern "C" void kernel_launch(void* const* d_in, const int* in_sizes, int n_in,
                              void* d_out, int out_size, void* d_ws, size_t ws_size,
                              hipStream_t stream) {
    const float* feat = (const float*)d_in[0];
    const float* ew   = (const float*)d_in[1];
    const float* W1   = (const float*)d_in[2];
    const float* b1   = (const float*)d_in[3];
    const float* W2   = (const float*)d_in[4];
    const float* b2   = (const float*)d_in[5];
    const float* ffW1 = (const float*)d_in[6];
    const float* ffb1 = (const float*)d_in[7];
    const float* ffW2 = (const float*)d_in[8];
    const float* ffb2 = (const float*)d_in[9];
    const float* ffW3 = (const float*)d_in[10];
    const float* ffb3 = (const float*)d_in[11];
    const float* ffWs = (const float*)d_in[12];
    const float* ffbs = (const float*)d_in[13];
    const int* esrc = (const int*)d_in[14];
    const int* edst = (const int*)d_in[15];
    const int* gid  = (const int*)d_in[16];

    const int N = in_sizes[0] / D;
    const int E = in_sizes[1];
    float* out = (float*)d_out;

    const int rpb = (N + NB - 1) / NB;        // 196 (<=256 required by bucket_sort)
    const int chunk = (E + NBLK - 1) / NBLK;  // 3125 edges per scatter block

    // workspace layout
    char* ws = (char*)d_ws;
    int2* ep = (int2*)ws;                                   // E int2 = 12.8MB
    unsigned short* A = (unsigned short*)(ep + E);          // N*128 bf16 = 25.6MB
    // build temporaries alias A (A written only after build completes)
    int2* tmp_sw = (int2*)A;                                // E int2 = 12.8MB
    unsigned short* tmp_lr = (unsigned short*)(tmp_sw + E); // E u16  =  3.2MB
    float* pooled = (float*)(A + (size_t)N * D);            // G*D
    float* ffo = pooled + G * D;                            // G*D
    int* gptr = (int*)(ffo + G * D);                        // G+1
    int* row_ptr = gptr + G + 2;                            // N+1
    int* bbase = row_ptr + N + 1;                           // NB+1
    int* bsum = bbase + NB + 1;                             // NB
    int* counts = bsum + NB;                                // NB*NBLK = 1MB

    float* S = out;  // fp32 SpMM result buffer

    const dim3 blk(256);
    const int gemmGrid = (N + 31) / 32;
    const int nGrid = (N + 255) / 256;

    // ---- CSR build (atomic-free radix partition; LDS atomics only)
    radix_count<<<NBLK, blk, 0, stream>>>(edst, counts, E, rpb, chunk);
    radix_scan_rel<<<NB, blk, 0, stream>>>(counts, bsum);
    radix_base<<<1, NB, 0, stream>>>(bsum, bbase, row_ptr, E, N);
    radix_scatter<<<NBLK, blk, 0, stream>>>(esrc, edst, ew, counts, bbase,
                                            tmp_sw, tmp_lr, E, rpb, chunk);
    bucket_sort<<<NB, blk, 0, stream>>>(tmp_lr, tmp_sw, bbase, ep, row_ptr, N, rpb);

    // ---- graph boundaries from sorted gid
    bounds_kernel<<<nGrid, blk, 0, stream>>>(gid, gptr, N);

    // ---- pipeline (A stored bf16; S fp32)
    gemm128<false><<<gemmGrid, blk, 0, stream>>>(feat, W1, nullptr, A, N);
    spmm_csr_bf16<<<(N + 3) / 4, blk, 0, stream>>>((const unsigned int*)A, ep, row_ptr, S, N);
    gemm128<true><<<gemmGrid, blk, 0, stream>>>(S, W2, b1, A, N);
    spmm_csr_bf16<<<(N + 3) / 4, blk, 0, stream>>>((const unsigned int*)A, ep, row_ptr, S, N);

    // ---- per-graph mean pool + FF + scatter
    pool_kernel<<<G, 512, 0, stream>>>(S, gptr, b2, pooled);
    ff_kernel<<<G, 128, 0, stream>>>(pooled, ffW1, ffb1, ffW2, ffb2,
                                     ffW3, ffb3, ffWs, ffbs, ffo);
    scatter_kernel<<<(int)(((size_t)N * 32 + 255) / 256), blk, 0, stream>>>(ffo, gid, out, N);
}

// Round 6
// 374.363 us; speedup vs baseline: 2.5544x; 1.3220x over previous
//
#include <hip/hip_runtime.h>
#include <math.h>

// ---------------------------------------------------------------------------
// Encoder: GCN(2 layers) + per-graph mean pool + FF MLP on pooled rows + sigmoid
// N=100000 nodes, E=1600000 edges, D=128, G=256 graphs (graph_id sorted)
// Round 6: replace fp32 vector GEMM (2x111us, VALU-issue-bound) with
// LDS-free MFMA bf16 GEMM:
//   - W^T held in 128 VGPRs/wave (loaded once from pre-transposed bf16 W)
//   - X streamed from global fp32, converted to bf16 frags in-register
//     (bias+relu fused for layer 2), fp32 MFMA accumulate, bf16 out.
//   - Same k-map used for A and B frags => k-permutation-safe vs HW layout.
// ---------------------------------------------------------------------------

#define D 128
#define G 256
#define NB 512     // dst buckets (rows-per-bucket = ceil(N/NB) = 196 <= 256)
#define NBLK 512   // scatter blocks (each owns a contiguous edge chunk)

typedef __attribute__((ext_vector_type(8))) short bf16x8;
typedef __attribute__((ext_vector_type(4))) float f32x4;

__device__ __forceinline__ unsigned short f2bf(float f) {
    unsigned u = __float_as_uint(f);
    unsigned r = (u + 0x7fffu + ((u >> 16) & 1u)) >> 16;   // round-nearest-even
    return (unsigned short)r;
}

// ---- one-time: WT[c][k] = bf16(W[k][c])  (128x128)
__global__ __launch_bounds__(256)
void prep_wt(const float* __restrict__ W, short* __restrict__ WT) {
    int idx = blockIdx.x * 256 + threadIdx.x;
    if (idx >= 128 * 128) return;
    int k = idx >> 7, c = idx & 127;
    WT[c * 128 + k] = (short)f2bf(W[k * 128 + c]);
}

// ---- MFMA GEMM: Y_bf16[nrows x 128] = transform(X_f32) @ W  (WT = W^T bf16)
// A-operand = W^T tile (outdim x k), held in registers for the whole wave.
// B-operand = X^T (k x node). C: col=lane&15 (node), row=4*(lane>>4)+reg.
template<bool BIAS_RELU>
__global__ __launch_bounds__(256, 2)
void gemm_mfma(const float* __restrict__ X, const short* __restrict__ WT,
               const float* __restrict__ bias, short* __restrict__ Y, int nrows) {
    const int lane = threadIdx.x & 63;
    const int lr = lane & 15;        // node-within-group / WT row-within-tile
    const int lq = lane >> 4;        // quarter-wave: k-block selector
    const int wid = blockIdx.x * 4 + (threadIdx.x >> 6);
    const int nwaves = gridDim.x * 4;
    const int ngroups = (nrows + 15) >> 4;

    // hoist all W^T fragments: wf[mt][ks], mt = outdim tile, ks = k step
    bf16x8 wf[8][4];
#pragma unroll
    for (int mt = 0; mt < 8; mt++)
#pragma unroll
        for (int ks = 0; ks < 4; ks++)
            wf[mt][ks] = *(const bf16x8*)(WT + (mt * 16 + lr) * 128 + ks * 32 + lq * 8);

    // hoist bias fragments (uniform across groups)
    float4 bv0[4], bv1[4];
    if (BIAS_RELU) {
#pragma unroll
        for (int ks = 0; ks < 4; ks++) {
            bv0[ks] = *(const float4*)(bias + ks * 32 + lq * 8);
            bv1[ks] = *(const float4*)(bias + ks * 32 + lq * 8 + 4);
        }
    }

    for (int g = wid; g < ngroups; g += nwaves) {
        int node = g * 16 + lr;
        int nrow = min(node, nrows - 1);
        const float* xp = X + (size_t)nrow * D + lq * 8;
        f32x4 acc[8];
#pragma unroll
        for (int mt = 0; mt < 8; mt++) acc[mt] = (f32x4){0.f, 0.f, 0.f, 0.f};

#pragma unroll
        for (int ks = 0; ks < 4; ks++) {
            float4 v0 = *(const float4*)(xp + ks * 32);
            float4 v1 = *(const float4*)(xp + ks * 32 + 4);
            if (BIAS_RELU) {
                v0.x = fmaxf(v0.x + bv0[ks].x, 0.f);
                v0.y = fmaxf(v0.y + bv0[ks].y, 0.f);
                v0.z = fmaxf(v0.z + bv0[ks].z, 0.f);
                v0.w = fmaxf(v0.w + bv0[ks].w, 0.f);
                v1.x = fmaxf(v1.x + bv1[ks].x, 0.f);
                v1.y = fmaxf(v1.y + bv1[ks].y, 0.f);
                v1.z = fmaxf(v1.z + bv1[ks].z, 0.f);
                v1.w = fmaxf(v1.w + bv1[ks].w, 0.f);
            }
            bf16x8 xb;
            xb[0] = (short)f2bf(v0.x);
            xb[1] = (short)f2bf(v0.y);
            xb[2] = (short)f2bf(v0.z);
            xb[3] = (short)f2bf(v0.w);
            xb[4] = (short)f2bf(v1.x);
            xb[5] = (short)f2bf(v1.y);
            xb[6] = (short)f2bf(v1.z);
            xb[7] = (short)f2bf(v1.w);
#pragma unroll
            for (int mt = 0; mt < 8; mt++)
                acc[mt] = __builtin_amdgcn_mfma_f32_16x16x32_bf16(wf[mt][ks], xb, acc[mt], 0, 0, 0);
        }

        if (node < nrows) {
            short* yp = Y + (size_t)node * D + lq * 4;
#pragma unroll
            for (int mt = 0; mt < 8; mt++) {
                ushort4 o;
                o.x = f2bf(acc[mt][0]);
                o.y = f2bf(acc[mt][1]);
                o.z = f2bf(acc[mt][2]);
                o.w = f2bf(acc[mt][3]);
                *(ushort4*)(yp + mt * 16) = o;
            }
        }
    }
}

// ============== CSR build: atomic-free radix partition + bucket sort ========

__global__ __launch_bounds__(256)
void radix_count(const int* __restrict__ dst, int* __restrict__ counts,
                 int ne, int rpb, int chunk) {
    __shared__ int h[NB];
    for (int i = threadIdx.x; i < NB; i += 256) h[i] = 0;
    __syncthreads();
    int b = blockIdx.x;
    int lo = b * chunk, hi = min(lo + chunk, ne);
    for (int e = lo + threadIdx.x; e < hi; e += 256)
        atomicAdd(&h[dst[e] / rpb], 1);
    __syncthreads();
    for (int k = threadIdx.x; k < NB; k += 256)
        counts[k * NBLK + b] = h[k];
}

__global__ __launch_bounds__(256)
void radix_scan_rel(int* __restrict__ counts, int* __restrict__ bsum) {
    __shared__ int s[256];
    int k = blockIdx.x, t = threadIdx.x;
    int base = k * NBLK + t * 2;
    int v0 = counts[base], v1 = counts[base + 1];
    int sum = v0 + v1;
    s[t] = sum;
    __syncthreads();
    for (int off = 1; off < 256; off <<= 1) {
        int x = (t >= off) ? s[t - off] : 0;
        __syncthreads();
        s[t] += x;
        __syncthreads();
    }
    int ex = s[t] - sum;
    counts[base] = ex;
    counts[base + 1] = ex + v0;
    if (t == 255) bsum[k] = s[255];
}

__global__ __launch_bounds__(NB)
void radix_base(const int* __restrict__ bsum, int* __restrict__ bbase,
                int* __restrict__ row_ptr, int ne, int n) {
    __shared__ int s[NB];
    int t = threadIdx.x;
    int v = bsum[t];
    s[t] = v;
    __syncthreads();
    for (int off = 1; off < NB; off <<= 1) {
        int x = (t >= off) ? s[t - off] : 0;
        __syncthreads();
        s[t] += x;
        __syncthreads();
    }
    bbase[t + 1] = s[t];
    if (t == 0) { bbase[0] = 0; row_ptr[n] = ne; }
}

__global__ __launch_bounds__(256)
void radix_scatter(const int* __restrict__ src, const int* __restrict__ dst,
                   const float* __restrict__ ew,
                   const int* __restrict__ counts, const int* __restrict__ bbase,
                   int2* __restrict__ tmp_sw, unsigned short* __restrict__ tmp_lr,
                   int ne, int rpb, int chunk) {
    __shared__ int cur[NB];
    int b = blockIdx.x;
    for (int k = threadIdx.x; k < NB; k += 256)
        cur[k] = bbase[k] + counts[k * NBLK + b];
    __syncthreads();
    int lo = b * chunk, hi = min(lo + chunk, ne);
    for (int e = lo + threadIdx.x; e < hi; e += 256) {
        int d = dst[e];
        int k = d / rpb;
        int pos = atomicAdd(&cur[k], 1);          // LDS atomic
        tmp_sw[pos] = make_int2(src[e], __float_as_int(ew[e]));
        tmp_lr[pos] = (unsigned short)(d - k * rpb);
    }
}

__global__ __launch_bounds__(256)
void bucket_sort(const unsigned short* __restrict__ tmp_lr,
                 const int2* __restrict__ tmp_sw,
                 const int* __restrict__ bbase, int2* __restrict__ ep,
                 int* __restrict__ row_ptr, int n, int rpb) {
    __shared__ int cnt[256], scn[256], cur[256];
    int b = blockIdx.x, t = threadIdx.x;
    int e0 = bbase[b], e1 = bbase[b + 1];
    int r0 = b * rpb;
    cnt[t] = 0;
    __syncthreads();
    for (int i = e0 + t; i < e1; i += 256)
        atomicAdd(&cnt[tmp_lr[i]], 1);
    __syncthreads();
    int v = cnt[t];
    scn[t] = v;
    __syncthreads();
    for (int off = 1; off < 256; off <<= 1) {
        int x = (t >= off) ? scn[t - off] : 0;
        __syncthreads();
        scn[t] += x;
        __syncthreads();
    }
    int ex = scn[t] - v;
    cur[t] = ex;
    int grow = r0 + t;
    if (t < rpb && grow < n) row_ptr[grow] = e0 + ex;
    __syncthreads();
    for (int i = e0 + t; i < e1; i += 256) {
        int r = tmp_lr[i];
        int pos = e0 + atomicAdd(&cur[r], 1);     // LDS atomic
        ep[pos] = tmp_sw[i];
    }
}

// ---- Row-parallel gather SpMM (bf16 X): one wave per row, lane owns 2 dims
__global__ __launch_bounds__(256)
void spmm_csr_bf16(const unsigned int* __restrict__ Xu, const int2* __restrict__ ep,
                   const int* __restrict__ rp, float* __restrict__ out, int nrows) {
    int row = blockIdx.x * 4 + (threadIdx.x >> 6);
    if (row >= nrows) return;
    int dp = threadIdx.x & 63;            // bf16-pair index (2 dims)
    int beg = rp[row], end = rp[row + 1];
    float a0x = 0.f, a0y = 0.f, a1x = 0.f, a1y = 0.f;
    int j = beg;
    for (; j + 1 < end; j += 2) {
        int2 e0 = ep[j], e1 = ep[j + 1];
        float w0 = __int_as_float(e0.y), w1 = __int_as_float(e1.y);
        unsigned u0 = Xu[(size_t)e0.x * 64 + dp];
        unsigned u1 = Xu[(size_t)e1.x * 64 + dp];
        a0x = fmaf(w0, __uint_as_float(u0 << 16), a0x);
        a0y = fmaf(w0, __uint_as_float(u0 & 0xffff0000u), a0y);
        a1x = fmaf(w1, __uint_as_float(u1 << 16), a1x);
        a1y = fmaf(w1, __uint_as_float(u1 & 0xffff0000u), a1y);
    }
    if (j < end) {
        int2 e0 = ep[j];
        float w0 = __int_as_float(e0.y);
        unsigned u0 = Xu[(size_t)e0.x * 64 + dp];
        a0x = fmaf(w0, __uint_as_float(u0 << 16), a0x);
        a0y = fmaf(w0, __uint_as_float(u0 & 0xffff0000u), a0y);
    }
    float2 r;
    r.x = a0x + a1x;
    r.y = a0y + a1y;
    *(float2*)(out + (size_t)row * D + dp * 2) = r;
}

// ======================= graph pooling + FF =================================

__global__ __launch_bounds__(256)
void bounds_kernel(const int* __restrict__ gid, int* __restrict__ ptr, int n) {
    int i = blockIdx.x * 256 + threadIdx.x;
    if (i >= n) return;
    int b = gid[i];
    int a = (i == 0) ? -1 : gid[i - 1];
    for (int g = a + 1; g <= b; g++) ptr[g] = i;
    if (i == n - 1) {
        for (int g = b + 1; g <= G; g++) ptr[g] = n;
    }
}

__global__ __launch_bounds__(512)
void pool_kernel(const float* __restrict__ S, const int* __restrict__ ptr,
                 const float* __restrict__ b2, float* __restrict__ pooled) {
    __shared__ float red[4][128];
    int g = blockIdx.x;
    int d = threadIdx.x & 127;
    int r = threadIdx.x >> 7;
    int beg = ptr[g], end = ptr[g + 1];
    float acc = 0.f;
    for (int n = beg + r; n < end; n += 4) acc += S[(size_t)n * D + d];
    red[r][d] = acc;
    __syncthreads();
    if (r == 0) {
        float s = red[0][d] + red[1][d] + red[2][d] + red[3][d];
        int cnt = end - beg;
        pooled[g * D + d] = (cnt > 0) ? (s / (float)cnt + b2[d]) : 0.f;
    }
}

__global__ __launch_bounds__(128)
void ff_kernel(const float* __restrict__ pooled,
               const float* __restrict__ W1, const float* __restrict__ b1,
               const float* __restrict__ W2, const float* __restrict__ b2,
               const float* __restrict__ W3, const float* __restrict__ b3,
               const float* __restrict__ Wsc, const float* __restrict__ bsc,
               float* __restrict__ ffout) {
    __shared__ float hx[D], za[D], zb[D];
    int g = blockIdx.x, d = threadIdx.x;
    hx[d] = pooled[g * D + d];
    __syncthreads();
    float s = b1[d];
    for (int k = 0; k < D; k++) s = fmaf(hx[k], W1[k * D + d], s);
    za[d] = fmaxf(s, 0.f);
    __syncthreads();
    s = b2[d];
    for (int k = 0; k < D; k++) s = fmaf(za[k], W2[k * D + d], s);
    zb[d] = fmaxf(s, 0.f);
    __syncthreads();
    s = b3[d];
    for (int k = 0; k < D; k++) s = fmaf(zb[k], W3[k * D + d], s);
    float z3 = fmaxf(s, 0.f);
    float sc = bsc[d];
    for (int k = 0; k < D; k++) sc = fmaf(hx[k], Wsc[k * D + d], sc);
    float v = z3 + sc;
    ffout[g * D + d] = 1.f / (1.f + expf(-v));
}

__global__ __launch_bounds__(256)
void scatter_kernel(const float* __restrict__ ffout, const int* __restrict__ gid,
                    float* __restrict__ out, int n) {
    unsigned idx = blockIdx.x * 256u + threadIdx.x;
    unsigned node = idx >> 5;
    if (node >= (unsigned)n) return;
    int d0 = (idx & 31) * 4;
    int g = gid[node];
    *(float4*)(out + (size_t)node * D + d0) = *(const float4*)(ffout + g * D + d0);
}

extern "C" void kernel_launch(void* const* d_in, const int* in_sizes, int n_in,
                              void* d_out, int out_size, void* d_ws, size_t ws_size,
                              hipStream_t stream) {
    const float* feat = (const float*)d_in[0];
    const float* ew   = (const float*)d_in[1];
    const float* W1   = (const float*)d_in[2];
    const float* b1   = (const float*)d_in[3];
    const float* W2   = (const float*)d_in[4];
    const float* b2   = (const float*)d_in[5];
    const float* ffW1 = (const float*)d_in[6];
    const float* ffb1 = (const float*)d_in[7];
    const float* ffW2 = (const float*)d_in[8];
    const float* ffb2 = (const float*)d_in[9];
    const float* ffW3 = (const float*)d_in[10];
    const float* ffb3 = (const float*)d_in[11];
    const float* ffWs = (const float*)d_in[12];
    const float* ffbs = (const float*)d_in[13];
    const int* esrc = (const int*)d_in[14];
    const int* edst = (const int*)d_in[15];
    const int* gid  = (const int*)d_in[16];

    const int N = in_sizes[0] / D;
    const int E = in_sizes[1];
    float* out = (float*)d_out;

    const int rpb = (N + NB - 1) / NB;        // 196 (<=256 required by bucket_sort)
    const int chunk = (E + NBLK - 1) / NBLK;  // edges per scatter block

    // workspace layout
    char* ws = (char*)d_ws;
    int2* ep = (int2*)ws;                                   // E int2 = 12.8MB
    unsigned short* A = (unsigned short*)(ep + E);          // N*128 bf16 = 25.6MB
    // build temporaries alias A (A written only after build completes)
    int2* tmp_sw = (int2*)A;                                // E int2 = 12.8MB
    unsigned short* tmp_lr = (unsigned short*)(tmp_sw + E); // E u16  =  3.2MB
    float* pooled = (float*)(A + (size_t)N * D);            // G*D
    float* ffo = pooled + G * D;                            // G*D
    int* gptr = (int*)(ffo + G * D);                        // G+1
    int* row_ptr = gptr + G + 2;                            // N+1
    int* bbase = row_ptr + N + 1;                           // NB+1
    int* bsum = bbase + NB + 1;                             // NB
    int* counts = bsum + NB;                                // NB*NBLK = 1MB
    short* WT1 = (short*)(counts + NB * NBLK);              // 128*128 bf16
    short* WT2 = WT1 + 128 * 128;                           // 128*128 bf16

    float* S = out;  // fp32 SpMM result buffer

    const dim3 blk(256);
    const int nGrid = (N + 255) / 256;

    // ---- weight transpose+bf16 (tiny, once per call)
    prep_wt<<<64, blk, 0, stream>>>(W1, WT1);
    prep_wt<<<64, blk, 0, stream>>>(W2, WT2);

    // ---- CSR build (atomic-free radix partition; LDS atomics only)
    radix_count<<<NBLK, blk, 0, stream>>>(edst, counts, E, rpb, chunk);
    radix_scan_rel<<<NB, blk, 0, stream>>>(counts, bsum);
    radix_base<<<1, NB, 0, stream>>>(bsum, bbase, row_ptr, E, N);
    radix_scatter<<<NBLK, blk, 0, stream>>>(esrc, edst, ew, counts, bbase,
                                            tmp_sw, tmp_lr, E, rpb, chunk);
    bucket_sort<<<NB, blk, 0, stream>>>(tmp_lr, tmp_sw, bbase, ep, row_ptr, N, rpb);

    // ---- graph boundaries from sorted gid
    bounds_kernel<<<nGrid, blk, 0, stream>>>(gid, gptr, N);

    // ---- pipeline (A stored bf16; S fp32)
    gemm_mfma<false><<<512, blk, 0, stream>>>(feat, WT1, nullptr, (short*)A, N);
    spmm_csr_bf16<<<(N + 3) / 4, blk, 0, stream>>>((const unsigned int*)A, ep, row_ptr, S, N);
    gemm_mfma<true><<<512, blk, 0, stream>>>(S, WT2, b1, (short*)A, N);
    spmm_csr_bf16<<<(N + 3) / 4, blk, 0, stream>>>((const unsigned int*)A, ep, row_ptr, S, N);

    // ---- per-graph mean pool + FF + scatter
    pool_kernel<<<G, 512, 0, stream>>>(S, gptr, b2, pooled);
    ff_kernel<<<G, 128, 0, stream>>>(pooled, ffW1, ffb1, ffW2, ffb2,
                                     ffW3, ffb3, ffWs, ffbs, ffo);
    scatter_kernel<<<(int)(((size_t)N * 32 + 255) / 256), blk, 0, stream>>>(ffo, gid, out, N);
}

// Round 7
// 320.211 us; speedup vs baseline: 2.9864x; 1.1691x over previous
//
#include <hip/hip_runtime.h>
#include <math.h>

// ---------------------------------------------------------------------------
// Encoder: GCN(2 layers) + per-graph mean pool + FF MLP on pooled rows + sigmoid
// N=100000 nodes, E=1600000 edges, D=128, G=256 graphs (graph_id sorted)
// Round 7: SpMM was latency-bound (0.026 loads/cyc/CU, VALU 33%, HBM 30%).
// New gather loop: coalesced per-lane metadata preload + __shfl broadcast
// (no load->address chain), half-wave per row with uint2 (4 dims)/lane,
// unroll 4 => many independent gathers in flight.
// ---------------------------------------------------------------------------

#define D 128
#define G 256
#define NB 512     // dst buckets (rows-per-bucket = ceil(N/NB) = 196 <= 256)
#define NBLK 512   // scatter blocks (each owns a contiguous edge chunk)

typedef __attribute__((ext_vector_type(8))) short bf16x8;
typedef __attribute__((ext_vector_type(4))) float f32x4;

__device__ __forceinline__ unsigned short f2bf(float f) {
    unsigned u = __float_as_uint(f);
    unsigned r = (u + 0x7fffu + ((u >> 16) & 1u)) >> 16;   // round-nearest-even
    return (unsigned short)r;
}

// ---- one-time: WT[c][k] = bf16(W[k][c])  (128x128)
__global__ __launch_bounds__(256)
void prep_wt(const float* __restrict__ W, short* __restrict__ WT) {
    int idx = blockIdx.x * 256 + threadIdx.x;
    if (idx >= 128 * 128) return;
    int k = idx >> 7, c = idx & 127;
    WT[c * 128 + k] = (short)f2bf(W[k * 128 + c]);
}

// ---- MFMA GEMM: Y_bf16[nrows x 128] = transform(X_f32) @ W  (WT = W^T bf16)
template<bool BIAS_RELU>
__global__ __launch_bounds__(256, 2)
void gemm_mfma(const float* __restrict__ X, const short* __restrict__ WT,
               const float* __restrict__ bias, short* __restrict__ Y, int nrows) {
    const int lane = threadIdx.x & 63;
    const int lr = lane & 15;        // node-within-group / WT row-within-tile
    const int lq = lane >> 4;        // quarter-wave: k-block selector
    const int wid = blockIdx.x * 4 + (threadIdx.x >> 6);
    const int nwaves = gridDim.x * 4;
    const int ngroups = (nrows + 15) >> 4;

    bf16x8 wf[8][4];
#pragma unroll
    for (int mt = 0; mt < 8; mt++)
#pragma unroll
        for (int ks = 0; ks < 4; ks++)
            wf[mt][ks] = *(const bf16x8*)(WT + (mt * 16 + lr) * 128 + ks * 32 + lq * 8);

    float4 bv0[4], bv1[4];
    if (BIAS_RELU) {
#pragma unroll
        for (int ks = 0; ks < 4; ks++) {
            bv0[ks] = *(const float4*)(bias + ks * 32 + lq * 8);
            bv1[ks] = *(const float4*)(bias + ks * 32 + lq * 8 + 4);
        }
    }

    for (int g = wid; g < ngroups; g += nwaves) {
        int node = g * 16 + lr;
        int nrow = min(node, nrows - 1);
        const float* xp = X + (size_t)nrow * D + lq * 8;
        f32x4 acc[8];
#pragma unroll
        for (int mt = 0; mt < 8; mt++) acc[mt] = (f32x4){0.f, 0.f, 0.f, 0.f};

#pragma unroll
        for (int ks = 0; ks < 4; ks++) {
            float4 v0 = *(const float4*)(xp + ks * 32);
            float4 v1 = *(const float4*)(xp + ks * 32 + 4);
            if (BIAS_RELU) {
                v0.x = fmaxf(v0.x + bv0[ks].x, 0.f);
                v0.y = fmaxf(v0.y + bv0[ks].y, 0.f);
                v0.z = fmaxf(v0.z + bv0[ks].z, 0.f);
                v0.w = fmaxf(v0.w + bv0[ks].w, 0.f);
                v1.x = fmaxf(v1.x + bv1[ks].x, 0.f);
                v1.y = fmaxf(v1.y + bv1[ks].y, 0.f);
                v1.z = fmaxf(v1.z + bv1[ks].z, 0.f);
                v1.w = fmaxf(v1.w + bv1[ks].w, 0.f);
            }
            bf16x8 xb;
            xb[0] = (short)f2bf(v0.x);
            xb[1] = (short)f2bf(v0.y);
            xb[2] = (short)f2bf(v0.z);
            xb[3] = (short)f2bf(v0.w);
            xb[4] = (short)f2bf(v1.x);
            xb[5] = (short)f2bf(v1.y);
            xb[6] = (short)f2bf(v1.z);
            xb[7] = (short)f2bf(v1.w);
#pragma unroll
            for (int mt = 0; mt < 8; mt++)
                acc[mt] = __builtin_amdgcn_mfma_f32_16x16x32_bf16(wf[mt][ks], xb, acc[mt], 0, 0, 0);
        }

        if (node < nrows) {
            short* yp = Y + (size_t)node * D + lq * 4;
#pragma unroll
            for (int mt = 0; mt < 8; mt++) {
                ushort4 o;
                o.x = f2bf(acc[mt][0]);
                o.y = f2bf(acc[mt][1]);
                o.z = f2bf(acc[mt][2]);
                o.w = f2bf(acc[mt][3]);
                *(ushort4*)(yp + mt * 16) = o;
            }
        }
    }
}

// ============== CSR build: atomic-free radix partition + bucket sort ========

__global__ __launch_bounds__(256)
void radix_count(const int* __restrict__ dst, int* __restrict__ counts,
                 int ne, int rpb, int chunk) {
    __shared__ int h[NB];
    for (int i = threadIdx.x; i < NB; i += 256) h[i] = 0;
    __syncthreads();
    int b = blockIdx.x;
    int lo = b * chunk, hi = min(lo + chunk, ne);
    for (int e = lo + threadIdx.x; e < hi; e += 256)
        atomicAdd(&h[dst[e] / rpb], 1);
    __syncthreads();
    for (int k = threadIdx.x; k < NB; k += 256)
        counts[k * NBLK + b] = h[k];
}

__global__ __launch_bounds__(256)
void radix_scan_rel(int* __restrict__ counts, int* __restrict__ bsum) {
    __shared__ int s[256];
    int k = blockIdx.x, t = threadIdx.x;
    int base = k * NBLK + t * 2;
    int v0 = counts[base], v1 = counts[base + 1];
    int sum = v0 + v1;
    s[t] = sum;
    __syncthreads();
    for (int off = 1; off < 256; off <<= 1) {
        int x = (t >= off) ? s[t - off] : 0;
        __syncthreads();
        s[t] += x;
        __syncthreads();
    }
    int ex = s[t] - sum;
    counts[base] = ex;
    counts[base + 1] = ex + v0;
    if (t == 255) bsum[k] = s[255];
}

__global__ __launch_bounds__(NB)
void radix_base(const int* __restrict__ bsum, int* __restrict__ bbase,
                int* __restrict__ row_ptr, int ne, int n) {
    __shared__ int s[NB];
    int t = threadIdx.x;
    int v = bsum[t];
    s[t] = v;
    __syncthreads();
    for (int off = 1; off < NB; off <<= 1) {
        int x = (t >= off) ? s[t - off] : 0;
        __syncthreads();
        s[t] += x;
        __syncthreads();
    }
    bbase[t + 1] = s[t];
    if (t == 0) { bbase[0] = 0; row_ptr[n] = ne; }
}

__global__ __launch_bounds__(256)
void radix_scatter(const int* __restrict__ src, const int* __restrict__ dst,
                   const float* __restrict__ ew,
                   const int* __restrict__ counts, const int* __restrict__ bbase,
                   int2* __restrict__ tmp_sw, unsigned short* __restrict__ tmp_lr,
                   int ne, int rpb, int chunk) {
    __shared__ int cur[NB];
    int b = blockIdx.x;
    for (int k = threadIdx.x; k < NB; k += 256)
        cur[k] = bbase[k] + counts[k * NBLK + b];
    __syncthreads();
    int lo = b * chunk, hi = min(lo + chunk, ne);
    for (int e = lo + threadIdx.x; e < hi; e += 256) {
        int d = dst[e];
        int k = d / rpb;
        int pos = atomicAdd(&cur[k], 1);          // LDS atomic
        tmp_sw[pos] = make_int2(src[e], __float_as_int(ew[e]));
        tmp_lr[pos] = (unsigned short)(d - k * rpb);
    }
}

__global__ __launch_bounds__(256)
void bucket_sort(const unsigned short* __restrict__ tmp_lr,
                 const int2* __restrict__ tmp_sw,
                 const int* __restrict__ bbase, int2* __restrict__ ep,
                 int* __restrict__ row_ptr, int n, int rpb) {
    __shared__ int cnt[256], scn[256], cur[256];
    int b = blockIdx.x, t = threadIdx.x;
    int e0 = bbase[b], e1 = bbase[b + 1];
    int r0 = b * rpb;
    cnt[t] = 0;
    __syncthreads();
    for (int i = e0 + t; i < e1; i += 256)
        atomicAdd(&cnt[tmp_lr[i]], 1);
    __syncthreads();
    int v = cnt[t];
    scn[t] = v;
    __syncthreads();
    for (int off = 1; off < 256; off <<= 1) {
        int x = (t >= off) ? scn[t - off] : 0;
        __syncthreads();
        scn[t] += x;
        __syncthreads();
    }
    int ex = scn[t] - v;
    cur[t] = ex;
    int grow = r0 + t;
    if (t < rpb && grow < n) row_ptr[grow] = e0 + ex;
    __syncthreads();
    for (int i = e0 + t; i < e1; i += 256) {
        int r = tmp_lr[i];
        int pos = e0 + atomicAdd(&cur[r], 1);     // LDS atomic
        ep[pos] = tmp_sw[i];
    }
}

// ---- Gather SpMM, MLP-optimized: half-wave (32 lanes) per row, uint2/lane.
// Metadata coalesced-preloaded per 32-edge tile, broadcast via __shfl.
__global__ __launch_bounds__(256)
void spmm_csr_bf16(const uint2* __restrict__ Xu2, const int2* __restrict__ ep,
                   const int* __restrict__ rp, float* __restrict__ out, int nrows) {
    int row = blockIdx.x * 8 + (threadIdx.x >> 5);
    if (row >= nrows) return;
    int l = threadIdx.x & 31;             // dim-quad index (4 dims)
    int beg = rp[row], end = rp[row + 1];
    float ax = 0.f, ay = 0.f, az = 0.f, aw = 0.f;

    for (int t0 = beg; t0 < end; t0 += 32) {
        int j = t0 + l;
        int2 e = (j < end) ? ep[j] : make_int2(0, 0);
        int cnt = min(32, end - t0);
#pragma unroll 4
        for (int t = 0; t < cnt; t++) {
            int s = __shfl(e.x, t, 32);
            float w = __shfl(__int_as_float(e.y), t, 32);
            uint2 u = Xu2[(size_t)s * 32 + l];
            ax = fmaf(w, __uint_as_float(u.x << 16), ax);
            ay = fmaf(w, __uint_as_float(u.x & 0xffff0000u), ay);
            az = fmaf(w, __uint_as_float(u.y << 16), az);
            aw = fmaf(w, __uint_as_float(u.y & 0xffff0000u), aw);
        }
    }
    float4 r = make_float4(ax, ay, az, aw);
    *(float4*)(out + (size_t)row * D + l * 4) = r;
}

// ======================= graph pooling + FF =================================

__global__ __launch_bounds__(256)
void bounds_kernel(const int* __restrict__ gid, int* __restrict__ ptr, int n) {
    int i = blockIdx.x * 256 + threadIdx.x;
    if (i >= n) return;
    int b = gid[i];
    int a = (i == 0) ? -1 : gid[i - 1];
    for (int g = a + 1; g <= b; g++) ptr[g] = i;
    if (i == n - 1) {
        for (int g = b + 1; g <= G; g++) ptr[g] = n;
    }
}

__global__ __launch_bounds__(512)
void pool_kernel(const float* __restrict__ S, const int* __restrict__ ptr,
                 const float* __restrict__ b2, float* __restrict__ pooled) {
    __shared__ float red[4][128];
    int g = blockIdx.x;
    int d = threadIdx.x & 127;
    int r = threadIdx.x >> 7;
    int beg = ptr[g], end = ptr[g + 1];
    float acc = 0.f;
    for (int n = beg + r; n < end; n += 4) acc += S[(size_t)n * D + d];
    red[r][d] = acc;
    __syncthreads();
    if (r == 0) {
        float s = red[0][d] + red[1][d] + red[2][d] + red[3][d];
        int cnt = end - beg;
        pooled[g * D + d] = (cnt > 0) ? (s / (float)cnt + b2[d]) : 0.f;
    }
}

__global__ __launch_bounds__(128)
void ff_kernel(const float* __restrict__ pooled,
               const float* __restrict__ W1, const float* __restrict__ b1,
               const float* __restrict__ W2, const float* __restrict__ b2,
               const float* __restrict__ W3, const float* __restrict__ b3,
               const float* __restrict__ Wsc, const float* __restrict__ bsc,
               float* __restrict__ ffout) {
    __shared__ float hx[D], za[D], zb[D];
    int g = blockIdx.x, d = threadIdx.x;
    hx[d] = pooled[g * D + d];
    __syncthreads();
    float s = b1[d];
    for (int k = 0; k < D; k++) s = fmaf(hx[k], W1[k * D + d], s);
    za[d] = fmaxf(s, 0.f);
    __syncthreads();
    s = b2[d];
    for (int k = 0; k < D; k++) s = fmaf(za[k], W2[k * D + d], s);
    zb[d] = fmaxf(s, 0.f);
    __syncthreads();
    s = b3[d];
    for (int k = 0; k < D; k++) s = fmaf(zb[k], W3[k * D + d], s);
    float z3 = fmaxf(s, 0.f);
    float sc = bsc[d];
    for (int k = 0; k < D; k++) sc = fmaf(hx[k], Wsc[k * D + d], sc);
    float v = z3 + sc;
    ffout[g * D + d] = 1.f / (1.f + expf(-v));
}

__global__ __launch_bounds__(256)
void scatter_kernel(const float* __restrict__ ffout, const int* __restrict__ gid,
                    float* __restrict__ out, int n) {
    unsigned idx = blockIdx.x * 256u + threadIdx.x;
    unsigned node = idx >> 5;
    if (node >= (unsigned)n) return;
    int d0 = (idx & 31) * 4;
    int g = gid[node];
    *(float4*)(out + (size_t)node * D + d0) = *(const float4*)(ffout + g * D + d0);
}

extern "C" void kernel_launch(void* const* d_in, const int* in_sizes, int n_in,
                              void* d_out, int out_size, void* d_ws, size_t ws_size,
                              hipStream_t stream) {
    const float* feat = (const float*)d_in[0];
    const float* ew   = (const float*)d_in[1];
    const float* W1   = (const float*)d_in[2];
    const float* b1   = (const float*)d_in[3];
    const float* W2   = (const float*)d_in[4];
    const float* b2   = (const float*)d_in[5];
    const float* ffW1 = (const float*)d_in[6];
    const float* ffb1 = (const float*)d_in[7];
    const float* ffW2 = (const float*)d_in[8];
    const float* ffb2 = (const float*)d_in[9];
    const float* ffW3 = (const float*)d_in[10];
    const float* ffb3 = (const float*)d_in[11];
    const float* ffWs = (const float*)d_in[12];
    const float* ffbs = (const float*)d_in[13];
    const int* esrc = (const int*)d_in[14];
    const int* edst = (const int*)d_in[15];
    const int* gid  = (const int*)d_in[16];

    const int N = in_sizes[0] / D;
    const int E = in_sizes[1];
    float* out = (float*)d_out;

    const int rpb = (N + NB - 1) / NB;        // 196 (<=256 required by bucket_sort)
    const int chunk = (E + NBLK - 1) / NBLK;  // edges per scatter block

    // workspace layout
    char* ws = (char*)d_ws;
    int2* ep = (int2*)ws;                                   // E int2 = 12.8MB
    unsigned short* A = (unsigned short*)(ep + E);          // N*128 bf16 = 25.6MB
    // build temporaries alias A (A written only after build completes)
    int2* tmp_sw = (int2*)A;                                // E int2 = 12.8MB
    unsigned short* tmp_lr = (unsigned short*)(tmp_sw + E); // E u16  =  3.2MB
    float* pooled = (float*)(A + (size_t)N * D);            // G*D
    float* ffo = pooled + G * D;                            // G*D
    int* gptr = (int*)(ffo + G * D);                        // G+1
    int* row_ptr = gptr + G + 2;                            // N+1
    int* bbase = row_ptr + N + 1;                           // NB+1
    int* bsum = bbase + NB + 1;                             // NB
    int* counts = bsum + NB;                                // NB*NBLK = 1MB
    short* WT1 = (short*)(counts + NB * NBLK);              // 128*128 bf16
    short* WT2 = WT1 + 128 * 128;                           // 128*128 bf16

    float* S = out;  // fp32 SpMM result buffer

    const dim3 blk(256);
    const int nGrid = (N + 255) / 256;

    // ---- weight transpose+bf16 (tiny, once per call)
    prep_wt<<<64, blk, 0, stream>>>(W1, WT1);
    prep_wt<<<64, blk, 0, stream>>>(W2, WT2);

    // ---- CSR build (atomic-free radix partition; LDS atomics only)
    radix_count<<<NBLK, blk, 0, stream>>>(edst, counts, E, rpb, chunk);
    radix_scan_rel<<<NB, blk, 0, stream>>>(counts, bsum);
    radix_base<<<1, NB, 0, stream>>>(bsum, bbase, row_ptr, E, N);
    radix_scatter<<<NBLK, blk, 0, stream>>>(esrc, edst, ew, counts, bbase,
                                            tmp_sw, tmp_lr, E, rpb, chunk);
    bucket_sort<<<NB, blk, 0, stream>>>(tmp_lr, tmp_sw, bbase, ep, row_ptr, N, rpb);

    // ---- graph boundaries from sorted gid
    bounds_kernel<<<nGrid, blk, 0, stream>>>(gid, gptr, N);

    // ---- pipeline (A stored bf16; S fp32)
    gemm_mfma<false><<<512, blk, 0, stream>>>(feat, WT1, nullptr, (short*)A, N);
    spmm_csr_bf16<<<(N + 7) / 8, blk, 0, stream>>>((const uint2*)A, ep, row_ptr, S, N);
    gemm_mfma<true><<<512, blk, 0, stream>>>(S, WT2, b1, (short*)A, N);
    spmm_csr_bf16<<<(N + 7) / 8, blk, 0, stream>>>((const uint2*)A, ep, row_ptr, S, N);

    // ---- per-graph mean pool + FF + scatter
    pool_kernel<<<G, 512, 0, stream>>>(S, gptr, b2, pooled);
    ff_kernel<<<G, 128, 0, stream>>>(pooled, ffW1, ffb1, ffW2, ffb2,
                                     ffW3, ffb3, ffWs, ffbs, ffo);
    scatter_kernel<<<(int)(((size_t)N * 32 + 255) / 256), blk, 0, stream>>>(ffo, gid, out, N);
}